// Round 4
// baseline (1008.053 us; speedup 1.0000x reference)
//
#include <hip/hip_runtime.h>
#include <cstdint>

#define BATCH_ 2048
#define IN_    512
#define HID_   1024
#define NL_    30

typedef _Float16 h8 __attribute__((ext_vector_type(8)));
typedef _Float16 h4 __attribute__((ext_vector_type(4)));
typedef float f4 __attribute__((ext_vector_type(4)));

// ---------------------------------------------------------------------------
// global -> LDS direct staging (16B per lane)
// ---------------------------------------------------------------------------
__device__ __forceinline__ void gload_lds16(const void* g, void* l) {
  __builtin_amdgcn_global_load_lds(
      (const __attribute__((address_space(1))) uint32_t*)g,
      (__attribute__((address_space(3))) uint32_t*)l, 16, 0, 0);
}

// ---------------------------------------------------------------------------
// Generic fp16 NT MFMA GEMM over up to 3 (A,B) pass pairs (split-fp16 trick):
//   acc = sum_p A_p @ B_p^T
// 64x64 tile, BK=64, 4 waves (2x2), wave = 32x32 (2x2 frags of 16x16x32).
// Double-buffered LDS via global_load_lds(16B), XOR chunk-swizzle applied on
// the GLOBAL source and on the ds_read address (both-sides rule).
// Epilogues:
//   H_GH : oh = (fp16)acc ; if (row==col) dG[row] = acc      (G = W@W^T)
//   H_C  : of = 0.1*dG[col] - 1.2*acc                        (C matrix)
//   H_OUT: of = acc                                          (decode)
// ---------------------------------------------------------------------------
enum { H_GH = 0, H_C = 1, H_OUT = 2 };

template <int EPI>
__global__ __launch_bounds__(256, 4) void hgemm_nt(
    const _Float16* __restrict__ A0, const _Float16* __restrict__ B0,
    const _Float16* __restrict__ A1, const _Float16* __restrict__ B1,
    const _Float16* __restrict__ A2, const _Float16* __restrict__ B2,
    int npass, int ktpp,  // K-tiles (of 64) per pass
    float* __restrict__ of, _Float16* __restrict__ oh, float* __restrict__ dG,
    int N, int K) {
  __shared__ char smem[2 * 16384];  // [buf][ A:8KB | B:8KB ]
  const int t = threadIdx.x;
  const int lane = t & 63;
  const int w = t >> 6;
  const int wm = w >> 1, wn = w & 1;
  const int m0 = blockIdx.y * 64, n0 = blockIdx.x * 64;

  // staging geometry (wave w stages segments {2w,2w+1} of A and of B)
  int srow[2], scol[2];
#pragma unroll
  for (int s2 = 0; s2 < 2; ++s2) {
    int p = (w * 2 + s2) * 1024 + lane * 16;
    int row = p >> 7;
    int c = ((p >> 4) & 7) ^ (row & 7);
    srow[s2] = row;
    scol[s2] = c * 8;
  }

  auto selA = [&](int p) { return p == 0 ? A0 : (p == 1 ? A1 : A2); };
  auto selB = [&](int p) { return p == 0 ? B0 : (p == 1 ? B1 : B2); };

  auto stage = [&](int buf, const _Float16* Ab, const _Float16* Bb, int kt) {
#pragma unroll
    for (int s2 = 0; s2 < 2; ++s2) {
      int seg = w * 2 + s2;
      const _Float16* ga = Ab + (size_t)(m0 + srow[s2]) * K + kt * 64 + scol[s2];
      gload_lds16(ga, smem + buf * 16384 + seg * 1024);
      const _Float16* gb = Bb + (size_t)(n0 + srow[s2]) * K + kt * 64 + scol[s2];
      gload_lds16(gb, smem + buf * 16384 + 8192 + seg * 1024);
    }
  };

  f4 acc[2][2];
#pragma unroll
  for (int i = 0; i < 2; i++)
#pragma unroll
    for (int j = 0; j < 2; j++) acc[i][j] = (f4){0.f, 0.f, 0.f, 0.f};

  const int fr = lane & 15;
  const int kg = lane >> 4;

  const int NTtot = npass * ktpp;
  stage(0, selA(0), selB(0), 0);
  int cur = 0, p = 0, kk = 0;
  for (int tt = 0; tt < NTtot; ++tt) {
    __syncthreads();  // drains vmcnt(0): buf[cur] staged
    int pn = p, kn = kk + 1;
    if (kn == ktpp) { kn = 0; pn = p + 1; }
    if (tt + 1 < NTtot) stage(cur ^ 1, selA(pn), selB(pn), kn);
    const char* Ab = smem + cur * 16384;
    const char* Bb = smem + cur * 16384 + 8192;
#pragma unroll
    for (int ks = 0; ks < 2; ++ks) {
      h8 af[2], bf[2];
#pragma unroll
      for (int i = 0; i < 2; i++) {
        int row = wm * 32 + i * 16 + fr;
        int c = (ks * 4 + kg) ^ (row & 7);
        af[i] = *(const h8*)(Ab + row * 128 + c * 16);
      }
#pragma unroll
      for (int j = 0; j < 2; j++) {
        int row = wn * 32 + j * 16 + fr;
        int c = (ks * 4 + kg) ^ (row & 7);
        bf[j] = *(const h8*)(Bb + row * 128 + c * 16);
      }
#pragma unroll
      for (int i = 0; i < 2; i++)
#pragma unroll
        for (int j = 0; j < 2; j++)
          acc[i][j] =
              __builtin_amdgcn_mfma_f32_16x16x32_f16(af[i], bf[j], acc[i][j], 0, 0, 0);
    }
    __syncthreads();
    cur ^= 1; p = pn; kk = kn;
  }

  // C/D layout: col=lane&15, row=(lane>>4)*4+reg  [m89-verified]
  const int orow = (lane >> 4) * 4;
  const int ocol = lane & 15;
#pragma unroll
  for (int i = 0; i < 2; i++) {
#pragma unroll
    for (int j = 0; j < 2; j++) {
      int col = n0 + wn * 32 + j * 16 + ocol;
#pragma unroll
      for (int r = 0; r < 4; r++) {
        int row = m0 + wm * 32 + i * 16 + orow + r;
        size_t idx = (size_t)row * N + col;
        float v = acc[i][j][r];
        if constexpr (EPI == H_GH) {
          oh[idx] = (_Float16)v;
          if (row == col) dG[row] = v;
        }
        if constexpr (EPI == H_C) of[idx] = 0.1f * dG[col] - 1.2f * v;
        if constexpr (EPI == H_OUT) of[idx] = v;
      }
    }
  }
}

// ---------------------------------------------------------------------------
// Iteration kernel: z = Xf - step * (Ah @ Bh^T + Cb), M=2048, N=K=1024.
// 64x64 tile, 4 waves (2x2), wave = 32x32. A (x_tmp fp16) staged via
// global_load_lds + XOR swizzle, double-buffered, ONE barrier per K-step.
// B (Gh, 2MB, L2-resident) loaded DIRECT global->VGPR in fragment layout,
// prefetched one K-step ahead into statically-named register sets.
// ---------------------------------------------------------------------------
__global__ __launch_bounds__(256, 2) void hmma_z(
    const _Float16* __restrict__ Ah, const _Float16* __restrict__ Bh,
    const float* __restrict__ Xf, const float* __restrict__ Cb,
    float* __restrict__ Z, const float* __restrict__ step_p) {
  constexpr int K = HID_, N = HID_;
  __shared__ char smem[2 * 8192];  // A tiles only
  const int t = threadIdx.x;
  const int lane = t & 63;
  const int w = t >> 6;
  const int wm = w >> 1, wn = w & 1;
  const int m0 = blockIdx.y * 64, n0 = blockIdx.x * 64;

  // A staging geometry: 64 rows x 128B = 8KB; wave w stages segs {2w,2w+1}
  int srow[2], scol[2];
#pragma unroll
  for (int s2 = 0; s2 < 2; ++s2) {
    int p = (w * 2 + s2) * 1024 + lane * 16;
    int row = p >> 7;
    int c = ((p >> 4) & 7) ^ (row & 7);
    srow[s2] = row;
    scol[s2] = c * 8;
  }

#define STAGEA(buf, kt)                                                       \
  do {                                                                        \
    _Pragma("unroll") for (int s2 = 0; s2 < 2; ++s2) {                        \
      gload_lds16(Ah + (size_t)(m0 + srow[s2]) * K + (kt) * 64 + scol[s2],    \
                  smem + (buf) * 8192 + (w * 2 + s2) * 1024);                 \
    }                                                                         \
  } while (0)

  const int fr = lane & 15;
  const int kg = lane >> 4;

  // B fragment row pointers (j = 0,1); frag load = 16B at k-offset
  const _Float16* Bp0 = Bh + (size_t)(n0 + wn * 32 + 0 * 16 + fr) * K + kg * 8;
  const _Float16* Bp1 = Bh + (size_t)(n0 + wn * 32 + 1 * 16 + fr) * K + kg * 8;

#define LOADB(dst, kt)                                                        \
  do {                                                                        \
    dst[0][0] = *(const h8*)(Bp0 + (kt) * 64);                                \
    dst[0][1] = *(const h8*)(Bp1 + (kt) * 64);                                \
    dst[1][0] = *(const h8*)(Bp0 + (kt) * 64 + 32);                           \
    dst[1][1] = *(const h8*)(Bp1 + (kt) * 64 + 32);                           \
  } while (0)

  f4 acc[2][2];
#pragma unroll
  for (int i = 0; i < 2; i++)
#pragma unroll
    for (int j = 0; j < 2; j++) acc[i][j] = (f4){0.f, 0.f, 0.f, 0.f};

#define COMPUTE(buf, breg)                                                    \
  do {                                                                        \
    const char* Ab = smem + (buf) * 8192;                                     \
    _Pragma("unroll") for (int ks = 0; ks < 2; ++ks) {                        \
      h8 af[2];                                                               \
      _Pragma("unroll") for (int i = 0; i < 2; i++) {                         \
        int row = wm * 32 + i * 16 + fr;                                      \
        int c = (ks * 4 + kg) ^ (row & 7);                                    \
        af[i] = *(const h8*)(Ab + row * 128 + c * 16);                        \
      }                                                                       \
      _Pragma("unroll") for (int i = 0; i < 2; i++)                           \
        _Pragma("unroll") for (int j = 0; j < 2; j++)                         \
          acc[i][j] = __builtin_amdgcn_mfma_f32_16x16x32_f16(                 \
              af[i], breg[ks][j], acc[i][j], 0, 0, 0);                        \
    }                                                                         \
  } while (0)

  constexpr int NT = K / 64;  // 16, even
  h8 bA[2][2], bB[2][2];
  STAGEA(0, 0);
  LOADB(bA, 0);
  for (int kt = 0; kt < NT; kt += 2) {
    __syncthreads();  // buf0 staged (vmcnt drained) & prior buf1 readers done
    if (kt + 1 < NT) {
      STAGEA(1, kt + 1);
      LOADB(bB, kt + 1);
    }
    COMPUTE(0, bA);
    __syncthreads();  // buf1 staged & buf0 readers (just above) done
    if (kt + 2 < NT) {
      STAGEA(0, kt + 2);
      LOADB(bA, kt + 2);
    }
    COMPUTE(1, bB);
  }
#undef STAGEA
#undef LOADB
#undef COMPUTE

  // Epilogue: C/D layout col=lane&15, row=(lane>>4)*4+reg
  const float stepv = *step_p;
  const int orow = (lane >> 4) * 4;
  const int ocol = lane & 15;
#pragma unroll
  for (int i = 0; i < 2; i++) {
#pragma unroll
    for (int j = 0; j < 2; j++) {
      int col = n0 + wn * 32 + j * 16 + ocol;
#pragma unroll
      for (int r = 0; r < 4; r++) {
        int row = m0 + wm * 32 + i * 16 + orow + r;
        size_t idx = (size_t)row * N + col;
        Z[idx] = Xf[idx] - stepv * (acc[i][j][r] + Cb[idx]);
      }
    }
  }
}

// ---------------------------------------------------------------------------
// f32 -> (hi fp16, lo fp16) split, 4 elems/thread
// ---------------------------------------------------------------------------
__global__ __launch_bounds__(256) void split_hl(const float* __restrict__ s,
                                                _Float16* __restrict__ hi,
                                                _Float16* __restrict__ lo) {
  int i = blockIdx.x * blockDim.x + threadIdx.x;
  float4 v = ((const float4*)s)[i];
  h4 h, l;
  h[0] = (_Float16)v.x; l[0] = (_Float16)(v.x - (float)h[0]);
  h[1] = (_Float16)v.y; l[1] = (_Float16)(v.y - (float)h[1]);
  h[2] = (_Float16)v.z; l[2] = (_Float16)(v.z - (float)h[2]);
  h[3] = (_Float16)v.w; l[3] = (_Float16)(v.w - (float)h[3]);
  ((h4*)hi)[i] = h;
  ((h4*)lo)[i] = l;
}

// ---------------------------------------------------------------------------
// W [1024][512] f32 -> WT hi/lo fp16 [512][1024]
// ---------------------------------------------------------------------------
__global__ __launch_bounds__(256) void transpose_split(
    const float* __restrict__ W, _Float16* __restrict__ WTh,
    _Float16* __restrict__ WTl) {
  __shared__ float tile[32][33];
  int bx = blockIdx.x * 32;  // k base
  int by = blockIdx.y * 32;  // h base
  int tx = threadIdx.x, ty = threadIdx.y;  // 32 x 8
#pragma unroll
  for (int i = 0; i < 32; i += 8)
    tile[ty + i][tx] = W[(size_t)(by + ty + i) * IN_ + bx + tx];
  __syncthreads();
#pragma unroll
  for (int i = 0; i < 32; i += 8) {
    float v = tile[tx][ty + i];
    _Float16 h = (_Float16)v;
    _Float16 l = (_Float16)(v - (float)h);
    WTh[(size_t)(bx + ty + i) * HID_ + by + tx] = h;
    WTl[(size_t)(bx + ty + i) * HID_ + by + tx] = l;
  }
}

// ---------------------------------------------------------------------------
// Sparsemax (Michelot exact simplex projection) + FISTA momentum.
// ONE WAVE PER ROW (16 f32/lane), shfl-only butterfly reductions, no LDS.
// negstep != nullptr => layer 0: v = -(*negstep) * zsrc  (z = -step*C fold).
// ---------------------------------------------------------------------------
__global__ __launch_bounds__(256) void sparsemax_w(
    const float* __restrict__ zsrc, const float* __restrict__ negstep,
    float* __restrict__ xold, float* __restrict__ xtmp,
    _Float16* __restrict__ xth, float mom) {
  const int lane = threadIdx.x & 63;
  const int row = blockIdx.x * 4 + (threadIdx.x >> 6);
  const float4* zr = (const float4*)(zsrc + (size_t)row * HID_);

  float sc = 1.f;
  if (negstep) sc = -(*negstep);

  float4 v[4];
#pragma unroll
  for (int i = 0; i < 4; i++) {
    float4 tv = zr[lane + 64 * i];
    v[i] = make_float4(sc * tv.x, sc * tv.y, sc * tv.z, sc * tv.w);
  }

  float s = 0.f;
#pragma unroll
  for (int i = 0; i < 4; i++) s += v[i].x + v[i].y + v[i].z + v[i].w;
#pragma unroll
  for (int o = 32; o; o >>= 1) s += __shfl_xor(s, o, 64);
  float tau = (s - 1.0f) * (1.0f / (float)HID_);

  int cprev = HID_ + 1024;
  for (int it = 0; it < 64; ++it) {
    float sp = 0.f, cp = 0.f;
#pragma unroll
    for (int i = 0; i < 4; i++) {
      if (v[i].x > tau) { sp += v[i].x; cp += 1.f; }
      if (v[i].y > tau) { sp += v[i].y; cp += 1.f; }
      if (v[i].z > tau) { sp += v[i].z; cp += 1.f; }
      if (v[i].w > tau) { sp += v[i].w; cp += 1.f; }
    }
#pragma unroll
    for (int o = 32; o; o >>= 1) {
      sp += __shfl_xor(sp, o, 64);
      cp += __shfl_xor(cp, o, 64);
    }
    int ci = (int)cp;
    tau = (sp - 1.0f) / cp;
    if (ci == cprev) break;
    cprev = ci;
  }

  float4* xo4 = (float4*)(xold + (size_t)row * HID_);
  float4* xt4 = (float4*)(xtmp + (size_t)row * HID_);
  h4* xh4 = (h4*)(xth + (size_t)row * HID_);
#pragma unroll
  for (int i = 0; i < 4; i++) {
    float4 xn = make_float4(fmaxf(v[i].x - tau, 0.f), fmaxf(v[i].y - tau, 0.f),
                            fmaxf(v[i].z - tau, 0.f), fmaxf(v[i].w - tau, 0.f));
    float4 xt = xn;
    if (mom > 0.f) {
      float4 xo = xo4[lane + 64 * i];
      xt.x = xn.x + mom * (xn.x - xo.x);
      xt.y = xn.y + mom * (xn.y - xo.y);
      xt.z = xn.z + mom * (xn.z - xo.z);
      xt.w = xn.w + mom * (xn.w - xo.w);
    }
    xo4[lane + 64 * i] = xn;
    xt4[lane + 64 * i] = xt;
    h4 hv;
    hv[0] = (_Float16)xt.x; hv[1] = (_Float16)xt.y;
    hv[2] = (_Float16)xt.z; hv[3] = (_Float16)xt.w;
    xh4[lane + 64 * i] = hv;
  }
}

// ---------------------------------------------------------------------------
extern "C" void kernel_launch(void* const* d_in, const int* in_sizes, int n_in,
                              void* d_out, int out_size, void* d_ws, size_t ws_size,
                              hipStream_t stream) {
  (void)in_sizes; (void)n_in; (void)out_size; (void)ws_size;
  const float* y      = (const float*)d_in[0];  // [2048,512]
  const float* W      = (const float*)d_in[1];  // [1024,512]
  const float* step_p = (const float*)d_in[2];  // scalar
  float* out = (float*)d_out;                   // [2048,512]

  float* ws = (float*)d_ws;
  float* Cb = ws;                        // 2M f32
  float* z  = Cb + 2097152;              // 2M f32
  float* xt = z + 2097152;               // 2M f32
  float* xo = xt + 2097152;              // 2M f32
  float* dG = xo + 2097152;              // 1024 f32 (pad 1024)
  _Float16* Gh  = (_Float16*)(dG + 1024);  // 1M h
  _Float16* yh  = Gh + 1048576;            // 1M h
  _Float16* yl  = yh + 1048576;            // 1M h
  _Float16* Wh  = yl + 1048576;            // 512K h
  _Float16* Wl  = Wh + 524288;             // 512K h
  _Float16* WTh = Wl + 524288;             // 512K h
  _Float16* WTl = WTh + 524288;            // 512K h
  // aliases (lifetime-disjoint):
  _Float16* xth = yh;           // x_tmp fp16 (2M h) over yh+yl (dead after C)
  _Float16* xoh = (_Float16*)z; // x_new hi (2M h) over z (dead after last layer)
  _Float16* xol = xoh + 2097152;

  dim3 blk(256);
  // input splits
  split_hl<<<dim3(BATCH_ * IN_ / 4 / 256), blk, 0, stream>>>(y, yh, yl);
  split_hl<<<dim3(HID_ * IN_ / 4 / 256), blk, 0, stream>>>(W, Wh, Wl);
  transpose_split<<<dim3(IN_ / 32, HID_ / 32), dim3(32, 8), 0, stream>>>(W, WTh, WTl);

  // Gh = fp16(Wh @ Wh^T), dG = diag (f32)   [single pass; feeds fp16 anyway]
  hgemm_nt<H_GH><<<dim3(HID_ / 64, HID_ / 64), blk, 0, stream>>>(
      Wh, Wh, nullptr, nullptr, nullptr, nullptr, 1, IN_ / 64,
      nullptr, Gh, dG, HID_, IN_);
  // Cb = 0.1*dG[n] - 1.2*(y @ W^T)  via split-fp16 (3 passes)
  // (P*||y||^2 row-const dropped: simplex projection is shift-invariant)
  hgemm_nt<H_C><<<dim3(HID_ / 64, BATCH_ / 64), blk, 0, stream>>>(
      yh, Wh, yl, Wh, yh, Wl, 3, IN_ / 64, Cb, nullptr, dG, HID_, IN_);

  // layer 0: z = -step*C folded into sparsemax; mom = 0
  sparsemax_w<<<dim3(BATCH_ / 4), blk, 0, stream>>>(Cb, step_p, xo, xt, xth, 0.f);

  for (int l = 1; l < NL_; ++l) {
    hmma_z<<<dim3(HID_ / 64, BATCH_ / 64), blk, 0, stream>>>(
        xth, Gh, xt, Cb, z, step_p);
    float mom = (float)l / ((float)l + 3.0f);
    sparsemax_w<<<dim3(BATCH_ / 4), blk, 0, stream>>>(z, nullptr, xo, xt, xth, mom);
  }

  // decode: out = x_new @ W = x_new @ WT^T  via split-fp16 (3 passes)
  split_hl<<<dim3(BATCH_ * HID_ / 4 / 256), blk, 0, stream>>>(xo, xoh, xol);
  hgemm_nt<H_OUT><<<dim3(IN_ / 64, BATCH_ / 64), blk, 0, stream>>>(
      xoh, WTh, xol, WTh, xoh, WTl, 3, HID_ / 64,
      out, nullptr, nullptr, IN_, HID_);
}

// Round 5
// 721.338 us; speedup vs baseline: 1.3975x; 1.3975x over previous
//
#include <hip/hip_runtime.h>
#include <cstdint>

#define BATCH_ 2048
#define IN_    512
#define HID_   1024
#define NL_    30

typedef _Float16 h8 __attribute__((ext_vector_type(8)));
typedef _Float16 h4 __attribute__((ext_vector_type(4)));
typedef float f4 __attribute__((ext_vector_type(4)));

// ---------------------------------------------------------------------------
// global -> LDS direct staging (16B per lane)
// ---------------------------------------------------------------------------
__device__ __forceinline__ void gload_lds16(const void* g, void* l) {
  __builtin_amdgcn_global_load_lds(
      (const __attribute__((address_space(1))) uint32_t*)g,
      (__attribute__((address_space(3))) uint32_t*)l, 16, 0, 0);
}

// ---------------------------------------------------------------------------
// Generic fp16 NT MFMA GEMM over up to 3 (A,B) pass pairs (split-fp16 trick):
//   acc = sum_p A_p @ B_p^T
// 64x64 tile, BK=64, 4 waves (2x2), wave = 32x32 (2x2 frags of 16x16x32).
// Double-buffered LDS via global_load_lds(16B), XOR chunk-swizzle applied on
// the GLOBAL source and on the ds_read address (both-sides rule).
// Epilogues:
//   H_GH : oh = (fp16)acc ; if (row==col) dG[row] = acc      (G = W@W^T)
//   H_C  : of = 0.1*dG[col] - 1.2*acc                        (C matrix)
//   H_OUT: of = acc                                          (decode)
// ---------------------------------------------------------------------------
enum { H_GH = 0, H_C = 1, H_OUT = 2 };

template <int EPI>
__global__ __launch_bounds__(256, 4) void hgemm_nt(
    const _Float16* __restrict__ A0, const _Float16* __restrict__ B0,
    const _Float16* __restrict__ A1, const _Float16* __restrict__ B1,
    const _Float16* __restrict__ A2, const _Float16* __restrict__ B2,
    int npass, int ktpp,  // K-tiles (of 64) per pass
    float* __restrict__ of, _Float16* __restrict__ oh, float* __restrict__ dG,
    int N, int K) {
  __shared__ char smem[2 * 16384];  // [buf][ A:8KB | B:8KB ]
  const int t = threadIdx.x;
  const int lane = t & 63;
  const int w = t >> 6;
  const int wm = w >> 1, wn = w & 1;
  const int m0 = blockIdx.y * 64, n0 = blockIdx.x * 64;

  // staging geometry (wave w stages segments {2w,2w+1} of A and of B)
  int srow[2], scol[2];
#pragma unroll
  for (int s2 = 0; s2 < 2; ++s2) {
    int p = (w * 2 + s2) * 1024 + lane * 16;
    int row = p >> 7;
    int c = ((p >> 4) & 7) ^ (row & 7);
    srow[s2] = row;
    scol[s2] = c * 8;
  }

  auto selA = [&](int p) { return p == 0 ? A0 : (p == 1 ? A1 : A2); };
  auto selB = [&](int p) { return p == 0 ? B0 : (p == 1 ? B1 : B2); };

  auto stage = [&](int buf, const _Float16* Ab, const _Float16* Bb, int kt) {
#pragma unroll
    for (int s2 = 0; s2 < 2; ++s2) {
      int seg = w * 2 + s2;
      const _Float16* ga = Ab + (size_t)(m0 + srow[s2]) * K + kt * 64 + scol[s2];
      gload_lds16(ga, smem + buf * 16384 + seg * 1024);
      const _Float16* gb = Bb + (size_t)(n0 + srow[s2]) * K + kt * 64 + scol[s2];
      gload_lds16(gb, smem + buf * 16384 + 8192 + seg * 1024);
    }
  };

  f4 acc[2][2];
#pragma unroll
  for (int i = 0; i < 2; i++)
#pragma unroll
    for (int j = 0; j < 2; j++) acc[i][j] = (f4){0.f, 0.f, 0.f, 0.f};

  const int fr = lane & 15;
  const int kg = lane >> 4;

  const int NTtot = npass * ktpp;
  stage(0, selA(0), selB(0), 0);
  int cur = 0, p = 0, kk = 0;
  for (int tt = 0; tt < NTtot; ++tt) {
    __syncthreads();  // drains vmcnt(0): buf[cur] staged
    int pn = p, kn = kk + 1;
    if (kn == ktpp) { kn = 0; pn = p + 1; }
    if (tt + 1 < NTtot) stage(cur ^ 1, selA(pn), selB(pn), kn);
    const char* Ab = smem + cur * 16384;
    const char* Bb = smem + cur * 16384 + 8192;
#pragma unroll
    for (int ks = 0; ks < 2; ++ks) {
      h8 af[2], bf[2];
#pragma unroll
      for (int i = 0; i < 2; i++) {
        int row = wm * 32 + i * 16 + fr;
        int c = (ks * 4 + kg) ^ (row & 7);
        af[i] = *(const h8*)(Ab + row * 128 + c * 16);
      }
#pragma unroll
      for (int j = 0; j < 2; j++) {
        int row = wn * 32 + j * 16 + fr;
        int c = (ks * 4 + kg) ^ (row & 7);
        bf[j] = *(const h8*)(Bb + row * 128 + c * 16);
      }
#pragma unroll
      for (int i = 0; i < 2; i++)
#pragma unroll
        for (int j = 0; j < 2; j++)
          acc[i][j] =
              __builtin_amdgcn_mfma_f32_16x16x32_f16(af[i], bf[j], acc[i][j], 0, 0, 0);
    }
    __syncthreads();
    cur ^= 1; p = pn; kk = kn;
  }

  // C/D layout: col=lane&15, row=(lane>>4)*4+reg  [m89-verified]
  const int orow = (lane >> 4) * 4;
  const int ocol = lane & 15;
#pragma unroll
  for (int i = 0; i < 2; i++) {
#pragma unroll
    for (int j = 0; j < 2; j++) {
      int col = n0 + wn * 32 + j * 16 + ocol;
#pragma unroll
      for (int r = 0; r < 4; r++) {
        int row = m0 + wm * 32 + i * 16 + orow + r;
        size_t idx = (size_t)row * N + col;
        float v = acc[i][j][r];
        if constexpr (EPI == H_GH) {
          oh[idx] = (_Float16)v;
          if (row == col) dG[row] = v;
        }
        if constexpr (EPI == H_C) of[idx] = 0.1f * dG[col] - 1.2f * v;
        if constexpr (EPI == H_OUT) of[idx] = v;
      }
    }
  }
}

// ---------------------------------------------------------------------------
// Iteration kernel: z = Xf - step * (Ah @ Bh^T + Cb), M=2048, N=K=1024.
// Round-3 operand plan (A and B both via global_load_lds + XOR swizzle), but
// 3-buffer pipeline with COUNTED vmcnt + raw s_barrier (T3/T4, m201 pattern):
//   iter k: s_waitcnt vmcnt(4)   -> my 4 buf[k] loads done (buf[k+1] flying)
//           s_barrier            -> all waves ditto => buf[k] fully staged,
//                                   and all waves finished COMPUTE(buf[k-1])
//           STAGE(buf[(k+2)%3])  -> restages the buffer freed at the barrier
//           COMPUTE(buf[k%3])
// vmcnt never drains to 0 in steady state; one barrier per K-step.
// ---------------------------------------------------------------------------
__global__ __launch_bounds__(256, 2) void hmma_z(
    const _Float16* __restrict__ Ah, const _Float16* __restrict__ Bh,
    const float* __restrict__ Xf, const float* __restrict__ Cb,
    float* __restrict__ Z, const float* __restrict__ step_p) {
  constexpr int K = HID_, N = HID_;
  __shared__ char smem[3 * 16384];  // 3 x [A:8KB | B:8KB]
  const int t = threadIdx.x;
  const int lane = t & 63;
  const int w = t >> 6;
  const int wm = w >> 1, wn = w & 1;
  const int m0 = blockIdx.y * 64, n0 = blockIdx.x * 64;

  int srow[2], scol[2];
#pragma unroll
  for (int s2 = 0; s2 < 2; ++s2) {
    int p = (w * 2 + s2) * 1024 + lane * 16;
    int row = p >> 7;
    int c = ((p >> 4) & 7) ^ (row & 7);
    srow[s2] = row;
    scol[s2] = c * 8;
  }

#define STAGE(buf, kt)                                                        \
  do {                                                                        \
    _Pragma("unroll") for (int s2 = 0; s2 < 2; ++s2) {                        \
      int seg = w * 2 + s2;                                                   \
      gload_lds16(Ah + (size_t)(m0 + srow[s2]) * K + (kt) * 64 + scol[s2],    \
                  smem + (buf) * 16384 + seg * 1024);                         \
      gload_lds16(Bh + (size_t)(n0 + srow[s2]) * K + (kt) * 64 + scol[s2],    \
                  smem + (buf) * 16384 + 8192 + seg * 1024);                  \
    }                                                                         \
  } while (0)

  f4 acc[2][2];
#pragma unroll
  for (int i = 0; i < 2; i++)
#pragma unroll
    for (int j = 0; j < 2; j++) acc[i][j] = (f4){0.f, 0.f, 0.f, 0.f};

  const int fr = lane & 15;
  const int kg = lane >> 4;

  constexpr int NT = K / 64;  // 16
  STAGE(0, 0);
  STAGE(1, 1);
  for (int kt = 0; kt < NT; ++kt) {
    if (kt + 1 < NT)
      asm volatile("s_waitcnt vmcnt(4)" ::: "memory");
    else
      asm volatile("s_waitcnt vmcnt(0)" ::: "memory");
    __builtin_amdgcn_s_barrier();
    if (kt + 2 < NT) STAGE((kt + 2) % 3, kt + 2);
    const char* Ab = smem + (kt % 3) * 16384;
    const char* Bb = Ab + 8192;
#pragma unroll
    for (int ks = 0; ks < 2; ++ks) {
      h8 af[2], bf[2];
#pragma unroll
      for (int i = 0; i < 2; i++) {
        int row = wm * 32 + i * 16 + fr;
        int c = (ks * 4 + kg) ^ (row & 7);
        af[i] = *(const h8*)(Ab + row * 128 + c * 16);
      }
#pragma unroll
      for (int j = 0; j < 2; j++) {
        int row = wn * 32 + j * 16 + fr;
        int c = (ks * 4 + kg) ^ (row & 7);
        bf[j] = *(const h8*)(Bb + row * 128 + c * 16);
      }
#pragma unroll
      for (int i = 0; i < 2; i++)
#pragma unroll
        for (int j = 0; j < 2; j++)
          acc[i][j] =
              __builtin_amdgcn_mfma_f32_16x16x32_f16(af[i], bf[j], acc[i][j], 0, 0, 0);
    }
  }
#undef STAGE

  // Epilogue: C/D layout col=lane&15, row=(lane>>4)*4+reg
  const float stepv = *step_p;
  const int orow = (lane >> 4) * 4;
  const int ocol = lane & 15;
#pragma unroll
  for (int i = 0; i < 2; i++) {
#pragma unroll
    for (int j = 0; j < 2; j++) {
      int col = n0 + wn * 32 + j * 16 + ocol;
#pragma unroll
      for (int r = 0; r < 4; r++) {
        int row = m0 + wm * 32 + i * 16 + orow + r;
        size_t idx = (size_t)row * N + col;
        Z[idx] = Xf[idx] - stepv * (acc[i][j][r] + Cb[idx]);
      }
    }
  }
}

// ---------------------------------------------------------------------------
// f32 -> (hi fp16, lo fp16) split, 4 elems/thread
// ---------------------------------------------------------------------------
__global__ __launch_bounds__(256) void split_hl(const float* __restrict__ s,
                                                _Float16* __restrict__ hi,
                                                _Float16* __restrict__ lo) {
  int i = blockIdx.x * blockDim.x + threadIdx.x;
  float4 v = ((const float4*)s)[i];
  h4 h, l;
  h[0] = (_Float16)v.x; l[0] = (_Float16)(v.x - (float)h[0]);
  h[1] = (_Float16)v.y; l[1] = (_Float16)(v.y - (float)h[1]);
  h[2] = (_Float16)v.z; l[2] = (_Float16)(v.z - (float)h[2]);
  h[3] = (_Float16)v.w; l[3] = (_Float16)(v.w - (float)h[3]);
  ((h4*)hi)[i] = h;
  ((h4*)lo)[i] = l;
}

// ---------------------------------------------------------------------------
// W [1024][512] f32 -> WT hi/lo fp16 [512][1024]
// ---------------------------------------------------------------------------
__global__ __launch_bounds__(256) void transpose_split(
    const float* __restrict__ W, _Float16* __restrict__ WTh,
    _Float16* __restrict__ WTl) {
  __shared__ float tile[32][33];
  int bx = blockIdx.x * 32;  // k base
  int by = blockIdx.y * 32;  // h base
  int tx = threadIdx.x, ty = threadIdx.y;  // 32 x 8
#pragma unroll
  for (int i = 0; i < 32; i += 8)
    tile[ty + i][tx] = W[(size_t)(by + ty + i) * IN_ + bx + tx];
  __syncthreads();
#pragma unroll
  for (int i = 0; i < 32; i += 8) {
    float v = tile[tx][ty + i];
    _Float16 h = (_Float16)v;
    _Float16 l = (_Float16)(v - (float)h);
    WTh[(size_t)(bx + ty + i) * HID_ + by + tx] = h;
    WTl[(size_t)(bx + ty + i) * HID_ + by + tx] = l;
  }
}

// ---------------------------------------------------------------------------
// Sparsemax (Michelot exact simplex projection) + FISTA momentum.
// ONE WAVE PER ROW (16 f32/lane), shfl-only butterfly reductions, no LDS.
// negstep != nullptr => layer 0: v = -(*negstep) * zsrc  (z = -step*C fold).
// ---------------------------------------------------------------------------
__global__ __launch_bounds__(256) void sparsemax_w(
    const float* __restrict__ zsrc, const float* __restrict__ negstep,
    float* __restrict__ xold, float* __restrict__ xtmp,
    _Float16* __restrict__ xth, float mom) {
  const int lane = threadIdx.x & 63;
  const int row = blockIdx.x * 4 + (threadIdx.x >> 6);
  const float4* zr = (const float4*)(zsrc + (size_t)row * HID_);

  float sc = 1.f;
  if (negstep) sc = -(*negstep);

  float4 v[4];
#pragma unroll
  for (int i = 0; i < 4; i++) {
    float4 tv = zr[lane + 64 * i];
    v[i] = make_float4(sc * tv.x, sc * tv.y, sc * tv.z, sc * tv.w);
  }

  float s = 0.f;
#pragma unroll
  for (int i = 0; i < 4; i++) s += v[i].x + v[i].y + v[i].z + v[i].w;
#pragma unroll
  for (int o = 32; o; o >>= 1) s += __shfl_xor(s, o, 64);
  float tau = (s - 1.0f) * (1.0f / (float)HID_);

  int cprev = HID_ + 1024;
  for (int it = 0; it < 64; ++it) {
    float sp = 0.f, cp = 0.f;
#pragma unroll
    for (int i = 0; i < 4; i++) {
      if (v[i].x > tau) { sp += v[i].x; cp += 1.f; }
      if (v[i].y > tau) { sp += v[i].y; cp += 1.f; }
      if (v[i].z > tau) { sp += v[i].z; cp += 1.f; }
      if (v[i].w > tau) { sp += v[i].w; cp += 1.f; }
    }
#pragma unroll
    for (int o = 32; o; o >>= 1) {
      sp += __shfl_xor(sp, o, 64);
      cp += __shfl_xor(cp, o, 64);
    }
    int ci = (int)cp;
    tau = (sp - 1.0f) / cp;
    if (ci == cprev) break;
    cprev = ci;
  }

  float4* xo4 = (float4*)(xold + (size_t)row * HID_);
  float4* xt4 = (float4*)(xtmp + (size_t)row * HID_);
  h4* xh4 = (h4*)(xth + (size_t)row * HID_);
#pragma unroll
  for (int i = 0; i < 4; i++) {
    float4 xn = make_float4(fmaxf(v[i].x - tau, 0.f), fmaxf(v[i].y - tau, 0.f),
                            fmaxf(v[i].z - tau, 0.f), fmaxf(v[i].w - tau, 0.f));
    float4 xt = xn;
    if (mom > 0.f) {
      float4 xo = xo4[lane + 64 * i];
      xt.x = xn.x + mom * (xn.x - xo.x);
      xt.y = xn.y + mom * (xn.y - xo.y);
      xt.z = xn.z + mom * (xn.z - xo.z);
      xt.w = xn.w + mom * (xn.w - xo.w);
    }
    xo4[lane + 64 * i] = xn;
    xt4[lane + 64 * i] = xt;
    h4 hv;
    hv[0] = (_Float16)xt.x; hv[1] = (_Float16)xt.y;
    hv[2] = (_Float16)xt.z; hv[3] = (_Float16)xt.w;
    xh4[lane + 64 * i] = hv;
  }
}

// ---------------------------------------------------------------------------
extern "C" void kernel_launch(void* const* d_in, const int* in_sizes, int n_in,
                              void* d_out, int out_size, void* d_ws, size_t ws_size,
                              hipStream_t stream) {
  (void)in_sizes; (void)n_in; (void)out_size; (void)ws_size;
  const float* y      = (const float*)d_in[0];  // [2048,512]
  const float* W      = (const float*)d_in[1];  // [1024,512]
  const float* step_p = (const float*)d_in[2];  // scalar
  float* out = (float*)d_out;                   // [2048,512]

  float* ws = (float*)d_ws;
  float* Cb = ws;                        // 2M f32
  float* z  = Cb + 2097152;              // 2M f32
  float* xt = z + 2097152;               // 2M f32
  float* xo = xt + 2097152;              // 2M f32
  float* dG = xo + 2097152;              // 1024 f32 (pad 1024)
  _Float16* Gh  = (_Float16*)(dG + 1024);  // 1M h
  _Float16* yh  = Gh + 1048576;            // 1M h
  _Float16* yl  = yh + 1048576;            // 1M h
  _Float16* Wh  = yl + 1048576;            // 512K h
  _Float16* Wl  = Wh + 524288;             // 512K h
  _Float16* WTh = Wl + 524288;             // 512K h
  _Float16* WTl = WTh + 524288;            // 512K h
  // aliases (lifetime-disjoint):
  _Float16* xth = yh;           // x_tmp fp16 (2M h) over yh+yl (dead after C)
  _Float16* xoh = (_Float16*)z; // x_new hi (2M h) over z (dead after last layer)
  _Float16* xol = xoh + 2097152;

  dim3 blk(256);
  // input splits
  split_hl<<<dim3(BATCH_ * IN_ / 4 / 256), blk, 0, stream>>>(y, yh, yl);
  split_hl<<<dim3(HID_ * IN_ / 4 / 256), blk, 0, stream>>>(W, Wh, Wl);
  transpose_split<<<dim3(IN_ / 32, HID_ / 32), dim3(32, 8), 0, stream>>>(W, WTh, WTl);

  // Gh = fp16(Wh @ Wh^T), dG = diag (f32)   [single pass; feeds fp16 anyway]
  hgemm_nt<H_GH><<<dim3(HID_ / 64, HID_ / 64), blk, 0, stream>>>(
      Wh, Wh, nullptr, nullptr, nullptr, nullptr, 1, IN_ / 64,
      nullptr, Gh, dG, HID_, IN_);
  // Cb = 0.1*dG[n] - 1.2*(y @ W^T)  via split-fp16 (3 passes)
  // (P*||y||^2 row-const dropped: simplex projection is shift-invariant)
  hgemm_nt<H_C><<<dim3(HID_ / 64, BATCH_ / 64), blk, 0, stream>>>(
      yh, Wh, yl, Wh, yh, Wl, 3, IN_ / 64, Cb, nullptr, dG, HID_, IN_);

  // layer 0: z = -step*C folded into sparsemax; mom = 0
  sparsemax_w<<<dim3(BATCH_ / 4), blk, 0, stream>>>(Cb, step_p, xo, xt, xth, 0.f);

  for (int l = 1; l < NL_; ++l) {
    hmma_z<<<dim3(HID_ / 64, BATCH_ / 64), blk, 0, stream>>>(
        xth, Gh, xt, Cb, z, step_p);
    float mom = (float)l / ((float)l + 3.0f);
    sparsemax_w<<<dim3(BATCH_ / 4), blk, 0, stream>>>(z, nullptr, xo, xt, xth, mom);
  }

  // decode: out = x_new @ W = x_new @ WT^T  via split-fp16 (3 passes)
  split_hl<<<dim3(BATCH_ * HID_ / 4 / 256), blk, 0, stream>>>(xo, xoh, xol);
  hgemm_nt<H_OUT><<<dim3(IN_ / 64, BATCH_ / 64), blk, 0, stream>>>(
      xoh, WTh, xol, WTh, xoh, WTl, 3, HID_ / 64,
      out, nullptr, nullptr, IN_, HID_);
}

// Round 6
// 698.761 us; speedup vs baseline: 1.4426x; 1.0323x over previous
//
#include <hip/hip_runtime.h>
#include <cstdint>

#define BATCH_ 2048
#define IN_    512
#define HID_   1024
#define NL_    30

typedef _Float16 h8 __attribute__((ext_vector_type(8)));
typedef _Float16 h4 __attribute__((ext_vector_type(4)));
typedef float f4 __attribute__((ext_vector_type(4)));

// ---------------------------------------------------------------------------
// global -> LDS direct staging (16B per lane)
// ---------------------------------------------------------------------------
__device__ __forceinline__ void gload_lds16(const void* g, void* l) {
  __builtin_amdgcn_global_load_lds(
      (const __attribute__((address_space(1))) uint32_t*)g,
      (__attribute__((address_space(3))) uint32_t*)l, 16, 0, 0);
}

// ---------------------------------------------------------------------------
// Generic fp16 NT MFMA GEMM over up to 3 (A,B) pass pairs (split-fp16 trick):
//   acc = sum_p A_p @ B_p^T
// 64x64 tile, BK=64, 4 waves (2x2), wave = 32x32 (2x2 frags of 16x16x32).
// Double-buffered LDS via global_load_lds(16B), XOR chunk-swizzle applied on
// the GLOBAL source and on the ds_read address (both-sides rule).
// Epilogues:
//   H_GH : oh = (fp16)acc ; if (row==col) dG[row] = acc      (G = W@W^T)
//   H_C  : of = 0.1*dG[col] - 1.2*acc                        (C matrix)
//   H_OUT: of = acc                                          (decode)
// ---------------------------------------------------------------------------
enum { H_GH = 0, H_C = 1, H_OUT = 2 };

template <int EPI>
__global__ __launch_bounds__(256, 4) void hgemm_nt(
    const _Float16* __restrict__ A0, const _Float16* __restrict__ B0,
    const _Float16* __restrict__ A1, const _Float16* __restrict__ B1,
    const _Float16* __restrict__ A2, const _Float16* __restrict__ B2,
    int npass, int ktpp,  // K-tiles (of 64) per pass
    float* __restrict__ of, _Float16* __restrict__ oh, float* __restrict__ dG,
    int N, int K) {
  __shared__ char smem[2 * 16384];  // [buf][ A:8KB | B:8KB ]
  const int t = threadIdx.x;
  const int lane = t & 63;
  const int w = t >> 6;
  const int wm = w >> 1, wn = w & 1;
  const int m0 = blockIdx.y * 64, n0 = blockIdx.x * 64;

  // staging geometry (wave w stages segments {2w,2w+1} of A and of B)
  int srow[2], scol[2];
#pragma unroll
  for (int s2 = 0; s2 < 2; ++s2) {
    int p = (w * 2 + s2) * 1024 + lane * 16;
    int row = p >> 7;
    int c = ((p >> 4) & 7) ^ (row & 7);
    srow[s2] = row;
    scol[s2] = c * 8;
  }

  auto selA = [&](int p) { return p == 0 ? A0 : (p == 1 ? A1 : A2); };
  auto selB = [&](int p) { return p == 0 ? B0 : (p == 1 ? B1 : B2); };

  auto stage = [&](int buf, const _Float16* Ab, const _Float16* Bb, int kt) {
#pragma unroll
    for (int s2 = 0; s2 < 2; ++s2) {
      int seg = w * 2 + s2;
      const _Float16* ga = Ab + (size_t)(m0 + srow[s2]) * K + kt * 64 + scol[s2];
      gload_lds16(ga, smem + buf * 16384 + seg * 1024);
      const _Float16* gb = Bb + (size_t)(n0 + srow[s2]) * K + kt * 64 + scol[s2];
      gload_lds16(gb, smem + buf * 16384 + 8192 + seg * 1024);
    }
  };

  f4 acc[2][2];
#pragma unroll
  for (int i = 0; i < 2; i++)
#pragma unroll
    for (int j = 0; j < 2; j++) acc[i][j] = (f4){0.f, 0.f, 0.f, 0.f};

  const int fr = lane & 15;
  const int kg = lane >> 4;

  const int NTtot = npass * ktpp;
  stage(0, selA(0), selB(0), 0);
  int cur = 0, p = 0, kk = 0;
  for (int tt = 0; tt < NTtot; ++tt) {
    __syncthreads();  // drains vmcnt(0): buf[cur] staged
    int pn = p, kn = kk + 1;
    if (kn == ktpp) { kn = 0; pn = p + 1; }
    if (tt + 1 < NTtot) stage(cur ^ 1, selA(pn), selB(pn), kn);
    const char* Ab = smem + cur * 16384;
    const char* Bb = smem + cur * 16384 + 8192;
#pragma unroll
    for (int ks = 0; ks < 2; ++ks) {
      h8 af[2], bf[2];
#pragma unroll
      for (int i = 0; i < 2; i++) {
        int row = wm * 32 + i * 16 + fr;
        int c = (ks * 4 + kg) ^ (row & 7);
        af[i] = *(const h8*)(Ab + row * 128 + c * 16);
      }
#pragma unroll
      for (int j = 0; j < 2; j++) {
        int row = wn * 32 + j * 16 + fr;
        int c = (ks * 4 + kg) ^ (row & 7);
        bf[j] = *(const h8*)(Bb + row * 128 + c * 16);
      }
#pragma unroll
      for (int i = 0; i < 2; i++)
#pragma unroll
        for (int j = 0; j < 2; j++)
          acc[i][j] =
              __builtin_amdgcn_mfma_f32_16x16x32_f16(af[i], bf[j], acc[i][j], 0, 0, 0);
    }
    __syncthreads();
    cur ^= 1; p = pn; kk = kn;
  }

  // C/D layout: col=lane&15, row=(lane>>4)*4+reg  [m89-verified]
  const int orow = (lane >> 4) * 4;
  const int ocol = lane & 15;
#pragma unroll
  for (int i = 0; i < 2; i++) {
#pragma unroll
    for (int j = 0; j < 2; j++) {
      int col = n0 + wn * 32 + j * 16 + ocol;
#pragma unroll
      for (int r = 0; r < 4; r++) {
        int row = m0 + wm * 32 + i * 16 + orow + r;
        size_t idx = (size_t)row * N + col;
        float v = acc[i][j][r];
        if constexpr (EPI == H_GH) {
          oh[idx] = (_Float16)v;
          if (row == col) dG[row] = v;
        }
        if constexpr (EPI == H_C) of[idx] = 0.1f * dG[col] - 1.2f * v;
        if constexpr (EPI == H_OUT) of[idx] = v;
      }
    }
  }
}

// ---------------------------------------------------------------------------
// Iteration kernel: z = Xf - step * (Ah @ Bh^T + Cb), M=2048, N=K=1024.
// 4-buffer / 3-ahead pipeline with COUNTED vmcnt + raw s_barrier:
//   iter k: s_waitcnt vmcnt(8)   -> oldest group (buf k) done; 2 groups fly
//           s_barrier            -> buf[k] staged block-wide, and all waves
//                                   finished reading buf[(k+3)%4]'s old data
//           STAGE(buf[(k+3)%4], kt+3)
//           COMPUTE(buf[k%4])
// Tail: vmcnt(4) at NT-2, vmcnt(0) at NT-1. LDS = 4 x 16KB = 64KB.
// Grid: 1-D 512 with XCD-chunked swizzle — XCD x owns m-panels 4x..4x+3
// (all 16 n-panels), so Gh (2MB) is reused 64x within one XCD's L2.
// ---------------------------------------------------------------------------
__global__ __launch_bounds__(256, 2) void hmma_z(
    const _Float16* __restrict__ Ah, const _Float16* __restrict__ Bh,
    const float* __restrict__ Xf, const float* __restrict__ Cb,
    float* __restrict__ Z, const float* __restrict__ step_p) {
  constexpr int K = HID_, N = HID_;
  __shared__ char smem[4 * 16384];  // 4 x [A:8KB | B:8KB]
  const int t = threadIdx.x;
  const int lane = t & 63;
  const int w = t >> 6;
  const int wm = w >> 1, wn = w & 1;

  // XCD-chunked swizzle: hw id -> (xcd = hw&7) owns logical chunk of 64
  const int hw = blockIdx.x;
  const int logical = (hw & 7) * 64 + (hw >> 3);
  const int m0 = (logical >> 4) * 64;   // 32 m-panels
  const int n0 = (logical & 15) * 64;   // 16 n-panels

  int srow[2], scol[2];
#pragma unroll
  for (int s2 = 0; s2 < 2; ++s2) {
    int p = (w * 2 + s2) * 1024 + lane * 16;
    int row = p >> 7;
    int c = ((p >> 4) & 7) ^ (row & 7);
    srow[s2] = row;
    scol[s2] = c * 8;
  }

#define STAGE(buf, kt)                                                        \
  do {                                                                        \
    _Pragma("unroll") for (int s2 = 0; s2 < 2; ++s2) {                        \
      int seg = w * 2 + s2;                                                   \
      gload_lds16(Ah + (size_t)(m0 + srow[s2]) * K + (kt) * 64 + scol[s2],    \
                  smem + (buf) * 16384 + seg * 1024);                         \
      gload_lds16(Bh + (size_t)(n0 + srow[s2]) * K + (kt) * 64 + scol[s2],    \
                  smem + (buf) * 16384 + 8192 + seg * 1024);                  \
    }                                                                         \
  } while (0)

  f4 acc[2][2];
#pragma unroll
  for (int i = 0; i < 2; i++)
#pragma unroll
    for (int j = 0; j < 2; j++) acc[i][j] = (f4){0.f, 0.f, 0.f, 0.f};

  const int fr = lane & 15;
  const int kg = lane >> 4;

  constexpr int NT = K / 64;  // 16
  STAGE(0, 0);
  STAGE(1, 1);
  STAGE(2, 2);
  for (int kt = 0; kt < NT; ++kt) {
    // groups in flight at entry: min(3, NT-kt); wait all but the newest ones
    if (kt < NT - 2)
      asm volatile("s_waitcnt vmcnt(8)" ::: "memory");
    else if (kt == NT - 2)
      asm volatile("s_waitcnt vmcnt(4)" ::: "memory");
    else
      asm volatile("s_waitcnt vmcnt(0)" ::: "memory");
    __builtin_amdgcn_sched_barrier(0);
    __builtin_amdgcn_s_barrier();
    __builtin_amdgcn_sched_barrier(0);
    if (kt + 3 < NT) STAGE((kt + 3) & 3, kt + 3);
    const char* Ab = smem + (kt & 3) * 16384;
    const char* Bb = Ab + 8192;
#pragma unroll
    for (int ks = 0; ks < 2; ++ks) {
      h8 af[2], bf[2];
#pragma unroll
      for (int i = 0; i < 2; i++) {
        int row = wm * 32 + i * 16 + fr;
        int c = (ks * 4 + kg) ^ (row & 7);
        af[i] = *(const h8*)(Ab + row * 128 + c * 16);
      }
#pragma unroll
      for (int j = 0; j < 2; j++) {
        int row = wn * 32 + j * 16 + fr;
        int c = (ks * 4 + kg) ^ (row & 7);
        bf[j] = *(const h8*)(Bb + row * 128 + c * 16);
      }
#pragma unroll
      for (int i = 0; i < 2; i++)
#pragma unroll
        for (int j = 0; j < 2; j++)
          acc[i][j] =
              __builtin_amdgcn_mfma_f32_16x16x32_f16(af[i], bf[j], acc[i][j], 0, 0, 0);
    }
  }
#undef STAGE

  // Epilogue: C/D layout col=lane&15, row=(lane>>4)*4+reg
  const float stepv = *step_p;
  const int orow = (lane >> 4) * 4;
  const int ocol = lane & 15;
#pragma unroll
  for (int i = 0; i < 2; i++) {
#pragma unroll
    for (int j = 0; j < 2; j++) {
      int col = n0 + wn * 32 + j * 16 + ocol;
#pragma unroll
      for (int r = 0; r < 4; r++) {
        int row = m0 + wm * 32 + i * 16 + orow + r;
        size_t idx = (size_t)row * N + col;
        Z[idx] = Xf[idx] - stepv * (acc[i][j][r] + Cb[idx]);
      }
    }
  }
}

// ---------------------------------------------------------------------------
// f32 -> (hi fp16, lo fp16) split, 4 elems/thread
// ---------------------------------------------------------------------------
__global__ __launch_bounds__(256) void split_hl(const float* __restrict__ s,
                                                _Float16* __restrict__ hi,
                                                _Float16* __restrict__ lo) {
  int i = blockIdx.x * blockDim.x + threadIdx.x;
  float4 v = ((const float4*)s)[i];
  h4 h, l;
  h[0] = (_Float16)v.x; l[0] = (_Float16)(v.x - (float)h[0]);
  h[1] = (_Float16)v.y; l[1] = (_Float16)(v.y - (float)h[1]);
  h[2] = (_Float16)v.z; l[2] = (_Float16)(v.z - (float)h[2]);
  h[3] = (_Float16)v.w; l[3] = (_Float16)(v.w - (float)h[3]);
  ((h4*)hi)[i] = h;
  ((h4*)lo)[i] = l;
}

// ---------------------------------------------------------------------------
// W [1024][512] f32 -> WT hi/lo fp16 [512][1024]
// ---------------------------------------------------------------------------
__global__ __launch_bounds__(256) void transpose_split(
    const float* __restrict__ W, _Float16* __restrict__ WTh,
    _Float16* __restrict__ WTl) {
  __shared__ float tile[32][33];
  int bx = blockIdx.x * 32;  // k base
  int by = blockIdx.y * 32;  // h base
  int tx = threadIdx.x, ty = threadIdx.y;  // 32 x 8
#pragma unroll
  for (int i = 0; i < 32; i += 8)
    tile[ty + i][tx] = W[(size_t)(by + ty + i) * IN_ + bx + tx];
  __syncthreads();
#pragma unroll
  for (int i = 0; i < 32; i += 8) {
    float v = tile[tx][ty + i];
    _Float16 h = (_Float16)v;
    _Float16 l = (_Float16)(v - (float)h);
    WTh[(size_t)(bx + ty + i) * HID_ + by + tx] = h;
    WTl[(size_t)(bx + ty + i) * HID_ + by + tx] = l;
  }
}

// ---------------------------------------------------------------------------
// Sparsemax (Michelot exact simplex projection) + FISTA momentum.
// ONE WAVE PER ROW (16 f32/lane), shfl-only butterfly reductions, no LDS.
// negstep != nullptr => layer 0: v = -(*negstep) * zsrc  (z = -step*C fold).
// ---------------------------------------------------------------------------
__global__ __launch_bounds__(256) void sparsemax_w(
    const float* __restrict__ zsrc, const float* __restrict__ negstep,
    float* __restrict__ xold, float* __restrict__ xtmp,
    _Float16* __restrict__ xth, float mom) {
  const int lane = threadIdx.x & 63;
  const int row = blockIdx.x * 4 + (threadIdx.x >> 6);
  const float4* zr = (const float4*)(zsrc + (size_t)row * HID_);

  float sc = 1.f;
  if (negstep) sc = -(*negstep);

  float4 v[4];
#pragma unroll
  for (int i = 0; i < 4; i++) {
    float4 tv = zr[lane + 64 * i];
    v[i] = make_float4(sc * tv.x, sc * tv.y, sc * tv.z, sc * tv.w);
  }

  float s = 0.f;
#pragma unroll
  for (int i = 0; i < 4; i++) s += v[i].x + v[i].y + v[i].z + v[i].w;
#pragma unroll
  for (int o = 32; o; o >>= 1) s += __shfl_xor(s, o, 64);
  float tau = (s - 1.0f) * (1.0f / (float)HID_);

  int cprev = HID_ + 1024;
  for (int it = 0; it < 64; ++it) {
    float sp = 0.f, cp = 0.f;
#pragma unroll
    for (int i = 0; i < 4; i++) {
      if (v[i].x > tau) { sp += v[i].x; cp += 1.f; }
      if (v[i].y > tau) { sp += v[i].y; cp += 1.f; }
      if (v[i].z > tau) { sp += v[i].z; cp += 1.f; }
      if (v[i].w > tau) { sp += v[i].w; cp += 1.f; }
    }
#pragma unroll
    for (int o = 32; o; o >>= 1) {
      sp += __shfl_xor(sp, o, 64);
      cp += __shfl_xor(cp, o, 64);
    }
    int ci = (int)cp;
    tau = (sp - 1.0f) / cp;
    if (ci == cprev) break;
    cprev = ci;
  }

  float4* xo4 = (float4*)(xold + (size_t)row * HID_);
  float4* xt4 = (float4*)(xtmp + (size_t)row * HID_);
  h4* xh4 = (h4*)(xth + (size_t)row * HID_);
#pragma unroll
  for (int i = 0; i < 4; i++) {
    float4 xn = make_float4(fmaxf(v[i].x - tau, 0.f), fmaxf(v[i].y - tau, 0.f),
                            fmaxf(v[i].z - tau, 0.f), fmaxf(v[i].w - tau, 0.f));
    float4 xt = xn;
    if (mom > 0.f) {
      float4 xo = xo4[lane + 64 * i];
      xt.x = xn.x + mom * (xn.x - xo.x);
      xt.y = xn.y + mom * (xn.y - xo.y);
      xt.z = xn.z + mom * (xn.z - xo.z);
      xt.w = xn.w + mom * (xn.w - xo.w);
    }
    xo4[lane + 64 * i] = xn;
    xt4[lane + 64 * i] = xt;
    h4 hv;
    hv[0] = (_Float16)xt.x; hv[1] = (_Float16)xt.y;
    hv[2] = (_Float16)xt.z; hv[3] = (_Float16)xt.w;
    xh4[lane + 64 * i] = hv;
  }
}

// ---------------------------------------------------------------------------
extern "C" void kernel_launch(void* const* d_in, const int* in_sizes, int n_in,
                              void* d_out, int out_size, void* d_ws, size_t ws_size,
                              hipStream_t stream) {
  (void)in_sizes; (void)n_in; (void)out_size; (void)ws_size;
  const float* y      = (const float*)d_in[0];  // [2048,512]
  const float* W      = (const float*)d_in[1];  // [1024,512]
  const float* step_p = (const float*)d_in[2];  // scalar
  float* out = (float*)d_out;                   // [2048,512]

  float* ws = (float*)d_ws;
  float* Cb = ws;                        // 2M f32
  float* z  = Cb + 2097152;              // 2M f32
  float* xt = z + 2097152;               // 2M f32
  float* xo = xt + 2097152;              // 2M f32
  float* dG = xo + 2097152;              // 1024 f32 (pad 1024)
  _Float16* Gh  = (_Float16*)(dG + 1024);  // 1M h
  _Float16* yh  = Gh + 1048576;            // 1M h
  _Float16* yl  = yh + 1048576;            // 1M h
  _Float16* Wh  = yl + 1048576;            // 512K h
  _Float16* Wl  = Wh + 524288;             // 512K h
  _Float16* WTh = Wl + 524288;             // 512K h
  _Float16* WTl = WTh + 524288;            // 512K h
  // aliases (lifetime-disjoint):
  _Float16* xth = yh;           // x_tmp fp16 (2M h) over yh+yl (dead after C)
  _Float16* xoh = (_Float16*)z; // x_new hi (2M h) over z (dead after last layer)
  _Float16* xol = xoh + 2097152;

  dim3 blk(256);
  // input splits
  split_hl<<<dim3(BATCH_ * IN_ / 4 / 256), blk, 0, stream>>>(y, yh, yl);
  split_hl<<<dim3(HID_ * IN_ / 4 / 256), blk, 0, stream>>>(W, Wh, Wl);
  transpose_split<<<dim3(IN_ / 32, HID_ / 32), dim3(32, 8), 0, stream>>>(W, WTh, WTl);

  // Gh = fp16(Wh @ Wh^T), dG = diag (f32)   [single pass; feeds fp16 anyway]
  hgemm_nt<H_GH><<<dim3(HID_ / 64, HID_ / 64), blk, 0, stream>>>(
      Wh, Wh, nullptr, nullptr, nullptr, nullptr, 1, IN_ / 64,
      nullptr, Gh, dG, HID_, IN_);
  // Cb = 0.1*dG[n] - 1.2*(y @ W^T)  via split-fp16 (3 passes)
  // (P*||y||^2 row-const dropped: simplex projection is shift-invariant)
  hgemm_nt<H_C><<<dim3(HID_ / 64, BATCH_ / 64), blk, 0, stream>>>(
      yh, Wh, yl, Wh, yh, Wl, 3, IN_ / 64, Cb, nullptr, dG, HID_, IN_);

  // layer 0: z = -step*C folded into sparsemax; mom = 0
  sparsemax_w<<<dim3(BATCH_ / 4), blk, 0, stream>>>(Cb, step_p, xo, xt, xth, 0.f);

  for (int l = 1; l < NL_; ++l) {
    hmma_z<<<dim3(512), blk, 0, stream>>>(xth, Gh, xt, Cb, z, step_p);
    float mom = (float)l / ((float)l + 3.0f);
    sparsemax_w<<<dim3(BATCH_ / 4), blk, 0, stream>>>(z, nullptr, xo, xt, xth, mom);
  }

  // decode: out = x_new @ W = x_new @ WT^T  via split-fp16 (3 passes)
  split_hl<<<dim3(BATCH_ * HID_ / 4 / 256), blk, 0, stream>>>(xo, xoh, xol);
  hgemm_nt<H_OUT><<<dim3(IN_ / 64, BATCH_ / 64), blk, 0, stream>>>(
      xoh, WTh, xol, WTh, xoh, WTl, 3, HID_ / 64,
      out, nullptr, nullptr, IN_, HID_);
}